// Round 3
// baseline (405.469 us; speedup 1.0000x reference)
//
#include <hip/hip_runtime.h>
#include <hip/hip_bf16.h>

#define NB 8
#define NU 8192
#define GN0 64
#define GN1 64
#define NS 4096          // GN0*GN1
#define NE 128
#define NH 8
#define NDH 16
#define CAP 20
#define NPTS (NB * NU)
#define OUT0 (NB * GN0 * GN1 * 2)   // 65536 f32 elements: xc_on passthrough

// ---------------------------------------------------------------------------
// ALL floating tensors are FLOAT32 (reference uses jax defaults; harness casts
// per reference dtype). Round 1/2 NaN: we treated f32 buffers as bf16.
//
// ws layout (bytes):
//   counts : NB*NS * 4                = 131072   @ 0
//   lists  : NB*NS*CAP * 2 (uint16)   = 1310720  @ 131072
// total = 1441792 bytes
// ---------------------------------------------------------------------------

__global__ __launch_bounds__(256) void nearest_kernel(
    const float* __restrict__ xc_off,
    const float* __restrict__ xc_on,
    int* __restrict__ counts, unsigned short* __restrict__ lists) {
  int idx = blockIdx.x * blockDim.x + threadIdx.x;   // 0..NPTS-1
  if (idx >= NPTS) return;
  int b = idx >> 13;                                 // idx / NU
  const float* g = xc_on + (size_t)b * (GN0 * GN1 * 2);
  float c00 = g[0];            // [b,0,0,0]
  float c01 = g[GN1 * 2];      // [b,1,0,0]
  float c10 = g[1];            // [b,0,0,1]
  float c11 = g[3];            // [b,0,1,1]
  float sp0 = c01 - c00;
  float sp1 = c11 - c10;
  float x0 = xc_off[(size_t)idx * 2 + 0];
  float x1 = xc_off[(size_t)idx * 2 + 1];
  float f0 = rintf((x0 - c00) / sp0);            // np.round = half-to-even
  float f1 = rintf((x1 - c10) / sp1);
  int i0 = (int)fminf(fmaxf(f0, 0.f), 63.f);
  int i1 = (int)fminf(fmaxf(f1, 0.f), 63.f);
  int cell = b * NS + i0 * GN1 + i1;
  int pos = atomicAdd(&counts[cell], 1);
  if (pos < CAP) lists[cell * CAP + pos] = (unsigned short)idx;
}

// copy xc_on (f32) -> out[0:OUT0] (f32), exact
__global__ __launch_bounds__(256) void copy0_kernel(
    const float* __restrict__ xc_on, float* __restrict__ out) {
  int i = blockIdx.x * blockDim.x + threadIdx.x;
  if (i < OUT0) out[i] = xc_on[i];
}

__global__ __launch_bounds__(128) void attn_kernel(
    const float* __restrict__ zc_off,
    const float* __restrict__ latents,
    const float* __restrict__ fake,
    const float* __restrict__ Wq,
    const float* __restrict__ Wk,
    const float* __restrict__ Wv,
    const float* __restrict__ Wo,
    const int* __restrict__ counts, const unsigned short* __restrict__ lists,
    float* __restrict__ out) {
  int cell = blockIdx.x;            // 0..NB*NS-1
  int e = threadIdx.x;              // 0..127
  int s = cell & (NS - 1);
  __shared__ float zbuf[CAP + 4][NE];   // raw tokens + fake (padded to x4)
  __shared__ float kbuf[CAP + 1][NE];   // projected K
  __shared__ float vbuf[CAP + 1][NE];   // projected V
  __shared__ float lrow[NE];            // latents row (q input)
  __shared__ float qrow[NE];            // projected q
  __shared__ float sc[NH][CAP + 1];
  __shared__ float ovec[NE];

  int cnt = min(counts[cell], CAP);
  int T = cnt + 1;                  // + fake token (always valid)

  lrow[e] = latents[(size_t)s * NE + e];
  for (int t = 0; t < cnt; ++t) {
    int p = lists[cell * CAP + t];
    zbuf[t][e] = zc_off[(size_t)p * NE + e];
  }
  zbuf[cnt][e] = fake[e];           // fake token joins the K/V projection
  int T4 = (T + 3) & ~3;
  for (int t = T; t < T4; ++t) zbuf[t][e] = 0.f;
  __syncthreads();

  // K/V projection (tokens incl. fake), 4 per pass to amortize weight reads
  for (int t0 = 0; t0 < T4; t0 += 4) {
    float ka[4] = {0.f, 0.f, 0.f, 0.f};
    float va[4] = {0.f, 0.f, 0.f, 0.f};
    for (int j = 0; j < NE; ++j) {
      float wk = Wk[j * NE + e];
      float wv = Wv[j * NE + e];
#pragma unroll
      for (int c = 0; c < 4; ++c) {
        float z = zbuf[t0 + c][j];
        ka[c] += z * wk;
        va[c] += z * wv;
      }
    }
#pragma unroll
    for (int c = 0; c < 4; ++c) {
      if (t0 + c < T) {
        kbuf[t0 + c][e] = ka[c];
        vbuf[t0 + c][e] = va[c];
      }
    }
  }
  // q projection: q[e] = sum_j latents[s][j] * Wq[j][e]
  {
    float qa = 0.f;
    for (int j = 0; j < NE; ++j)
      qa += lrow[j] * Wq[j * NE + e];
    qrow[e] = qa;
  }
  __syncthreads();

  // scores: idx enumerates (t, h); dh = 16, scale = 1/sqrt(16)
  for (int idx = e; idx < T * NH; idx += 128) {
    int t = idx >> 3;
    int h = idx & 7;
    float acc = 0.f;
#pragma unroll
    for (int d = 0; d < NDH; ++d)
      acc += qrow[h * NDH + d] * kbuf[t][h * NDH + d];
    sc[h][t] = acc * 0.25f;
  }
  __syncthreads();

  // softmax per head (T is tiny, avg ~3)
  if (e < NH) {
    float m = -1e30f;
    for (int t = 0; t < T; ++t) m = fmaxf(m, sc[e][t]);
    float sum = 0.f;
    for (int t = 0; t < T; ++t) {
      float w = __expf(sc[e][t] - m);
      sum += w;
      sc[e][t] = w;
    }
    float inv = 1.f / sum;
    for (int t = 0; t < T; ++t) sc[e][t] *= inv;
  }
  __syncthreads();

  // PV
  {
    int h = e >> 4;
    float acc = 0.f;
    for (int t = 0; t < T; ++t) acc += sc[h][t] * vbuf[t][e];
    ovec[e] = acc;
  }
  __syncthreads();

  // Wo epilogue
  float z = 0.f;
  for (int j = 0; j < NE; ++j)
    z += ovec[j] * Wo[j * NE + e];
  out[(size_t)OUT0 + (size_t)cell * NE + e] = z;
}

extern "C" void kernel_launch(void* const* d_in, const int* in_sizes, int n_in,
                              void* d_out, int out_size, void* d_ws, size_t ws_size,
                              hipStream_t stream) {
  const float* xc_off  = (const float*)d_in[0];
  const float* xc_on   = (const float*)d_in[1];
  const float* zc_off  = (const float*)d_in[2];
  // d_in[3] = zc_on_grid (unused), d_in[10] = used_modality (unused)
  const float* latents = (const float*)d_in[4];
  const float* fake    = (const float*)d_in[5];
  const float* Wq      = (const float*)d_in[6];
  const float* Wk      = (const float*)d_in[7];
  const float* Wv      = (const float*)d_in[8];
  const float* Wo      = (const float*)d_in[9];
  float* out = (float*)d_out;

  char* ws = (char*)d_ws;
  int* counts = (int*)(ws);
  unsigned short* lists = (unsigned short*)(ws + 131072);

  hipMemsetAsync(counts, 0, 131072, stream);
  hipLaunchKernelGGL(nearest_kernel, dim3((NPTS + 255) / 256), dim3(256), 0, stream,
                     xc_off, xc_on, counts, lists);
  hipLaunchKernelGGL(copy0_kernel, dim3((OUT0 + 255) / 256), dim3(256), 0, stream,
                     xc_on, out);
  hipLaunchKernelGGL(attn_kernel, dim3(NB * NS), dim3(128), 0, stream,
                     zc_off, latents, fake, Wq, Wk, Wv, Wo, counts, lists, out);
}

// Round 4
// 177.538 us; speedup vs baseline: 2.2838x; 2.2838x over previous
//
#include <hip/hip_runtime.h>
#include <hip/hip_bf16.h>

#define NB 8
#define NU 8192
#define GN0 64
#define GN1 64
#define NS 4096          // GN0*GN1
#define NE 128
#define NH 8
#define NDH 16
#define CAP 20
#define NPTS (NB * NU)               // 65536
#define NCELL (NB * NS)              // 32768
#define OUT0 (NB * GN0 * GN1 * 2)    // 65536 f32: xc_on passthrough

// ---------------------------------------------------------------------------
// ws layout (bytes):
//   counts : NB*NS*4            = 131072    @ 0
//   lists  : NB*NS*CAP*2 (u16)  = 1310720   @ 131072
//   Qf     : NS*NE*4 (f32)      = 2097152   @ 1441792
//   fakeKV : 2*NE*4 (f32)       = 1024      @ 3538944
//   Kb     : NPTS*NE*2 (bf16)   = 16777216  @ 3539968
//   Vb     : NPTS*NE*2 (bf16)   = 16777216  @ 20317184
// total = 37094400 (~35.4 MB)
// ---------------------------------------------------------------------------

__global__ __launch_bounds__(256) void nearest_kernel(
    const float* __restrict__ xc_off,
    const float* __restrict__ xc_on,
    int* __restrict__ counts, unsigned short* __restrict__ lists) {
  int idx = blockIdx.x * blockDim.x + threadIdx.x;
  if (idx >= NPTS) return;
  int b = idx >> 13;
  const float* g = xc_on + (size_t)b * (GN0 * GN1 * 2);
  float c00 = g[0], c01 = g[GN1 * 2], c10 = g[1], c11 = g[3];
  float sp0 = c01 - c00, sp1 = c11 - c10;
  float x0 = xc_off[(size_t)idx * 2 + 0];
  float x1 = xc_off[(size_t)idx * 2 + 1];
  float f0 = rintf((x0 - c00) / sp0);     // np.round = half-to-even
  float f1 = rintf((x1 - c10) / sp1);
  int i0 = (int)fminf(fmaxf(f0, 0.f), 63.f);
  int i1 = (int)fminf(fmaxf(f1, 0.f), 63.f);
  int cell = b * NS + i0 * GN1 + i1;
  int pos = atomicAdd(&counts[cell], 1);
  if (pos < CAP) lists[cell * CAP + pos] = (unsigned short)idx;
}

__global__ __launch_bounds__(256) void copy0_kernel(
    const float* __restrict__ xc_on, float* __restrict__ out) {
  int i = blockIdx.x * blockDim.x + threadIdx.x;
  if (i < OUT0) out[i] = xc_on[i];
}

// Q = latents @ Wq (4096 rows); block NS computes fake K/V row
__global__ __launch_bounds__(128) void qproj_kernel(
    const float* __restrict__ latents, const float* __restrict__ fake,
    const float* __restrict__ Wq, const float* __restrict__ Wk,
    const float* __restrict__ Wv,
    float* __restrict__ Qf, float* __restrict__ fakeKV) {
  int e = threadIdx.x;
  __shared__ float row[NE];
  if ((int)blockIdx.x < NS) {
    row[e] = latents[(size_t)blockIdx.x * NE + e];
    __syncthreads();
    float acc = 0.f;
    for (int j = 0; j < NE; ++j) acc += row[j] * Wq[j * NE + e];
    Qf[(size_t)blockIdx.x * NE + e] = acc;
  } else {
    row[e] = fake[e];
    __syncthreads();
    float ak = 0.f, av = 0.f;
    for (int j = 0; j < NE; ++j) {
      float z = row[j];
      ak += z * Wk[j * NE + e];
      av += z * Wv[j * NE + e];
    }
    fakeKV[e] = ak;
    fakeKV[NE + e] = av;
  }
}

// C[65536 x 256] = Z[65536 x 128] @ [Wk | Wv]; C stored bf16 into Kb / Vb.
// BM=BN=BK=64, 256 threads, 4x4 micro-tile.
__global__ __launch_bounds__(256) void kv_gemm(
    const float* __restrict__ Z, const float* __restrict__ Wk,
    const float* __restrict__ Wv,
    __hip_bfloat16* __restrict__ Kb, __hip_bfloat16* __restrict__ Vb) {
  __shared__ float As[64][68];   // pad 68: 16B-aligned rows, 2-way banks max
  __shared__ float Bs[64][68];
  int bx = blockIdx.x & 3;       // 0,1 -> Wk cols; 2,3 -> Wv cols
  int by = blockIdx.x >> 2;      // 0..1023
  int tid = threadIdx.x;
  int tx = tid & 15, ty = tid >> 4;
  const float* W = (bx < 2) ? Wk : Wv;
  int cbase = (bx & 1) * 64;
  float acc[4][4] = {{0.f}};
  for (int kt = 0; kt < 2; ++kt) {
    int k4 = tid & 15;
    int r0 = tid >> 4;
    for (int rr = r0; rr < 64; rr += 16) {
      float4 va = *(const float4*)&Z[(size_t)(by * 64 + rr) * NE + kt * 64 + k4 * 4];
      *(float4*)&As[rr][k4 * 4] = va;
      float4 vb = *(const float4*)&W[(size_t)(kt * 64 + rr) * NE + cbase + k4 * 4];
      *(float4*)&Bs[rr][k4 * 4] = vb;
    }
    __syncthreads();
    for (int k = 0; k < 64; ++k) {
      float b4[4];
      *(float4*)b4 = *(const float4*)&Bs[k][tx * 4];
#pragma unroll
      for (int i = 0; i < 4; ++i) {
        float a = As[ty * 4 + i][k];
#pragma unroll
        for (int j = 0; j < 4; ++j) acc[i][j] += a * b4[j];
      }
    }
    __syncthreads();
  }
  __hip_bfloat16* C = (bx < 2) ? Kb : Vb;
#pragma unroll
  for (int i = 0; i < 4; ++i) {
    size_t r = (size_t)(by * 64 + ty * 4 + i);
#pragma unroll
    for (int j = 0; j < 4; ++j)
      C[r * NE + cbase + tx * 4 + j] = __float2bfloat16(acc[i][j]);
  }
}

// per-cell: gather K, scores, softmax, PV -> write pre-Wo O into out buffer
__global__ __launch_bounds__(128) void attn2_kernel(
    const __hip_bfloat16* __restrict__ Kb, const __hip_bfloat16* __restrict__ Vb,
    const float* __restrict__ Qf, const float* __restrict__ fakeKV,
    const int* __restrict__ counts, const unsigned short* __restrict__ lists,
    float* __restrict__ out) {
  int cell = blockIdx.x;
  int e = threadIdx.x;
  int s = cell & (NS - 1);
  __shared__ float qrow[NE];
  __shared__ float kbuf[CAP + 1][NE];
  __shared__ float sc[NH][CAP + 1];
  int cnt = min(counts[cell], CAP);
  int T = cnt + 1;
  qrow[e] = Qf[(size_t)s * NE + e];
  for (int t = 0; t < cnt; ++t) {
    int p = lists[cell * CAP + t];
    kbuf[t][e] = __bfloat162float(Kb[(size_t)p * NE + e]);
  }
  kbuf[cnt][e] = fakeKV[e];
  __syncthreads();
  for (int idx = e; idx < T * NH; idx += 128) {
    int t = idx >> 3, h = idx & 7;
    float acc = 0.f;
#pragma unroll
    for (int d = 0; d < NDH; ++d)
      acc += qrow[h * NDH + d] * kbuf[t][h * NDH + d];
    sc[h][t] = acc * 0.25f;
  }
  __syncthreads();
  if (e < NH) {
    float m = -1e30f;
    for (int t = 0; t < T; ++t) m = fmaxf(m, sc[e][t]);
    float sum = 0.f;
    for (int t = 0; t < T; ++t) {
      float w = __expf(sc[e][t] - m);
      sum += w;
      sc[e][t] = w;
    }
    float inv = 1.f / sum;
    for (int t = 0; t < T; ++t) sc[e][t] *= inv;
  }
  __syncthreads();
  int h = e >> 4;
  float acc = 0.f;
  for (int t = 0; t < cnt; ++t) {
    int p = lists[cell * CAP + t];
    acc += sc[h][t] * __bfloat162float(Vb[(size_t)p * NE + e]);
  }
  acc += sc[h][cnt] * fakeKV[NE + e];
  out[(size_t)OUT0 + (size_t)cell * NE + e] = acc;
}

// in-place: out_rows = O_rows @ Wo ; 64 rows per block, all 128 cols
__global__ __launch_bounds__(256) void wo_gemm(
    const float* __restrict__ Wo, float* __restrict__ out) {
  __shared__ float Os[64][132];    // pad 132: 16B-aligned, 2-way banks
  int blk = blockIdx.x;            // 0..511
  int tid = threadIdx.x;
  float* base = out + (size_t)OUT0 + (size_t)blk * 64 * NE;
  {
    int k4 = tid & 31;             // 32 float4 per row
    int r0 = tid >> 5;             // 0..7
    for (int rr = r0; rr < 64; rr += 8) {
      float4 v = *(const float4*)&base[(size_t)rr * NE + k4 * 4];
      *(float4*)&Os[rr][k4 * 4] = v;
    }
  }
  __syncthreads();
  int tx = tid & 15, ty = tid >> 4;      // cols tx*8..+7, rows ty*4..+3
  float acc[4][8] = {{0.f}};
  for (int k = 0; k < NE; ++k) {
    float b8[8];
    *(float4*)&b8[0] = *(const float4*)&Wo[k * NE + tx * 8];
    *(float4*)&b8[4] = *(const float4*)&Wo[k * NE + tx * 8 + 4];
#pragma unroll
    for (int i = 0; i < 4; ++i) {
      float a = Os[ty * 4 + i][k];
#pragma unroll
      for (int j = 0; j < 8; ++j) acc[i][j] += a * b8[j];
    }
  }
#pragma unroll
  for (int i = 0; i < 4; ++i)
#pragma unroll
    for (int j = 0; j < 8; ++j)
      base[(size_t)(ty * 4 + i) * NE + tx * 8 + j] = acc[i][j];
}

extern "C" void kernel_launch(void* const* d_in, const int* in_sizes, int n_in,
                              void* d_out, int out_size, void* d_ws, size_t ws_size,
                              hipStream_t stream) {
  const float* xc_off  = (const float*)d_in[0];
  const float* xc_on   = (const float*)d_in[1];
  const float* zc_off  = (const float*)d_in[2];
  const float* latents = (const float*)d_in[4];
  const float* fake    = (const float*)d_in[5];
  const float* Wq      = (const float*)d_in[6];
  const float* Wk      = (const float*)d_in[7];
  const float* Wv      = (const float*)d_in[8];
  const float* Wo      = (const float*)d_in[9];
  float* out = (float*)d_out;

  char* ws = (char*)d_ws;
  int*            counts = (int*)(ws);
  unsigned short* lists  = (unsigned short*)(ws + 131072);
  float*          Qf     = (float*)(ws + 1441792);
  float*          fakeKV = (float*)(ws + 3538944);
  __hip_bfloat16* Kb     = (__hip_bfloat16*)(ws + 3539968);
  __hip_bfloat16* Vb     = (__hip_bfloat16*)(ws + 20317184);

  hipMemsetAsync(counts, 0, 131072, stream);
  hipLaunchKernelGGL(nearest_kernel, dim3((NPTS + 255) / 256), dim3(256), 0, stream,
                     xc_off, xc_on, counts, lists);
  hipLaunchKernelGGL(copy0_kernel, dim3((OUT0 + 255) / 256), dim3(256), 0, stream,
                     xc_on, out);
  hipLaunchKernelGGL(qproj_kernel, dim3(NS + 1), dim3(128), 0, stream,
                     latents, fake, Wq, Wk, Wv, Qf, fakeKV);
  hipLaunchKernelGGL(kv_gemm, dim3(1024 * 4), dim3(256), 0, stream,
                     zc_off, Wk, Wv, Kb, Vb);
  hipLaunchKernelGGL(attn2_kernel, dim3(NCELL), dim3(128), 0, stream,
                     Kb, Vb, Qf, fakeKV, counts, lists, out);
  hipLaunchKernelGGL(wo_gemm, dim3(NCELL / 64), dim3(256), 0, stream,
                     Wo, out);
}

// Round 5
// 138.046 us; speedup vs baseline: 2.9372x; 1.2861x over previous
//
#include <hip/hip_runtime.h>
#include <hip/hip_bf16.h>

#define NB 8
#define NU 8192
#define GN0 64
#define GN1 64
#define NS 4096
#define NE 128
#define NH 8
#define CAP 20
#define NPTS (NB * NU)               // 65536
#define NCELL (NB * NS)              // 32768
#define OUT0 (NB * GN0 * GN1 * 2)    // 65536 f32 passthrough

// ---------------------------------------------------------------------------
// ws layout (bytes), total ~27.7 MB (< proven-working 35.4 MB):
//   counts @ 0        (131072)   int32 per cell
//   lists  @ 131072   (1310720)  u16 point ids per cell
//   S      @ 1441792  (2097152)  f32 scores [NPTS][8] (pre-scaled by 0.25)
//   G      @ 3538944  (8388608)  bf16 [NS][8][128]: Wk_h @ q_{s,h}
//   FS     @ 11927552 (131072)   f32 [NS][8] fake-token scores (pre-scaled)
//   fakeKV @ 12058624 (1024)     f32 fakeK[128], fakeV[128]
//   Wvt    @ 12059648 (32768)    bf16 Wv^T [col][k]
//   Vb     @ 12092416 (16777216) bf16 V = Z @ Wv
//   ps     @ 28869632 (131072)   u16 per-point s-index
// ---------------------------------------------------------------------------

typedef __attribute__((ext_vector_type(8))) short short8v;
typedef __attribute__((ext_vector_type(4))) float float4v;

static __device__ inline unsigned pk2(float a, float b) {
  __hip_bfloat16 x = __float2bfloat16(a), y = __float2bfloat16(b);
  return ((unsigned)*(unsigned short*)&y << 16) | *(unsigned short*)&x;
}

__global__ __launch_bounds__(256) void nearest_kernel(
    const float* __restrict__ xc_off, const float* __restrict__ xc_on,
    int* __restrict__ counts, unsigned short* __restrict__ lists,
    unsigned short* __restrict__ ps) {
  int idx = blockIdx.x * blockDim.x + threadIdx.x;
  if (idx >= NPTS) return;
  int b = idx >> 13;
  const float* g = xc_on + (size_t)b * (GN0 * GN1 * 2);
  float c00 = g[0], c01 = g[GN1 * 2], c10 = g[1], c11 = g[3];
  float x0 = xc_off[(size_t)idx * 2 + 0];
  float x1 = xc_off[(size_t)idx * 2 + 1];
  float f0 = rintf((x0 - c00) / (c01 - c00));   // np.round = RNE
  float f1 = rintf((x1 - c10) / (c11 - c10));
  int i0 = (int)fminf(fmaxf(f0, 0.f), 63.f);
  int i1 = (int)fminf(fmaxf(f1, 0.f), 63.f);
  int s = i0 * GN1 + i1;
  ps[idx] = (unsigned short)s;
  int cell = b * NS + s;
  int pos = atomicAdd(&counts[cell], 1);
  if (pos < CAP) lists[cell * CAP + pos] = (unsigned short)idx;
}

__global__ __launch_bounds__(256) void copy0_kernel(
    const float* __restrict__ xc_on, float* __restrict__ out) {
  int i = blockIdx.x * blockDim.x + threadIdx.x;
  if (i < OUT0) out[i] = xc_on[i];
}

// one block: fakeK/fakeV rows + Wv^T bf16
__global__ __launch_bounds__(256) void tiny_prep(
    const float* __restrict__ fake, const float* __restrict__ Wk,
    const float* __restrict__ Wv,
    float* __restrict__ fakeKV, __hip_bfloat16* __restrict__ Wvt) {
  int t = threadIdx.x;
  __shared__ float frow[NE];
  if (t < NE) frow[t] = fake[t];
  __syncthreads();
  {
    int e = t & 127, half = t >> 7;
    const float* W = half ? Wv : Wk;
    float acc = 0.f;
    for (int j = 0; j < NE; ++j) acc += frow[j] * W[j * NE + e];
    fakeKV[half * NE + e] = acc;
  }
  for (int n = 0; n < 64; ++n) {
    int flat = n * 256 + t;              // 0..16383
    int j = flat >> 7, e = flat & 127;
    Wvt[e * NE + j] = __float2bfloat16(Wv[flat]);
  }
}

// per 8 latent rows: q = latent @ Wq (kept in LDS), then G[s][h][:] and FS
__global__ __launch_bounds__(256) void prep_kernel(
    const float* __restrict__ latents, const float* __restrict__ Wq,
    const float* __restrict__ Wk, const float* __restrict__ fakeKV,
    __hip_bfloat16* __restrict__ G, float* __restrict__ FS) {
  int s0 = blockIdx.x * 8;
  int tid = threadIdx.x;
  __shared__ float lrow[8][NE];
  __shared__ float qs[8][NE];
  for (int i = tid; i < 8 * NE; i += 256)
    lrow[i >> 7][i & 127] = latents[(size_t)s0 * NE + i];
  __syncthreads();
  for (int i = tid; i < 8 * NE; i += 256) {
    int sl = i >> 7, e = i & 127;
    float acc = 0.f;
    for (int j = 0; j < NE; ++j) acc += lrow[sl][j] * Wq[j * NE + e];
    qs[sl][e] = acc;
  }
  __syncthreads();
  int j = tid & 127, half = tid >> 7;
  for (int hh = 0; hh < 4; ++hh) {
    int h = half * 4 + hh;
    float wkr[16];
#pragma unroll
    for (int d = 0; d < 16; ++d) wkr[d] = Wk[j * NE + h * 16 + d];
    for (int sl = 0; sl < 8; ++sl) {
      float acc = 0.f;
#pragma unroll
      for (int d = 0; d < 16; ++d) acc += wkr[d] * qs[sl][h * 16 + d];
      G[((size_t)(s0 + sl) * 8 + h) * NE + j] = __float2bfloat16(acc);
    }
  }
  if (tid < 64) {
    int sl = tid >> 3, h = tid & 7;
    float acc = 0.f;
#pragma unroll
    for (int d = 0; d < 16; ++d) acc += qs[sl][h * 16 + d] * fakeKV[h * 16 + d];
    FS[(size_t)(s0 + sl) * 8 + h] = acc * 0.25f;
  }
}

// one wave per point: 8 head scores via z . G[s,h], butterfly reduce
__global__ __launch_bounds__(256) void scores_kernel(
    const float* __restrict__ z, const unsigned short* __restrict__ ps,
    const __hip_bfloat16* __restrict__ G, float* __restrict__ S) {
  int p = blockIdx.x * 4 + (threadIdx.x >> 6);
  int l = threadIdx.x & 63;
  int s = ps[p];
  float z0 = z[(size_t)p * NE + l], z1 = z[(size_t)p * NE + 64 + l];
  const __hip_bfloat16* g = G + (size_t)s * (8 * NE);
  float ph[8];
#pragma unroll
  for (int h = 0; h < 8; ++h) {
    float g0 = __bfloat162float(g[h * NE + l]);
    float g1 = __bfloat162float(g[h * NE + 64 + l]);
    ph[h] = z0 * g0 + z1 * g1;
  }
#pragma unroll
  for (int h = 0; h < 8; ++h)
#pragma unroll
    for (int off = 32; off; off >>= 1) ph[h] += __shfl_xor(ph[h], off);
  if (l == 0) {
    float4 a = {ph[0] * 0.25f, ph[1] * 0.25f, ph[2] * 0.25f, ph[3] * 0.25f};
    float4 b = {ph[4] * 0.25f, ph[5] * 0.25f, ph[6] * 0.25f, ph[7] * 0.25f};
    *(float4*)&S[(size_t)p * 8] = a;
    *(float4*)&S[(size_t)p * 8 + 4] = b;
  }
}

// V = bf16(Z @ Wv) via MFMA 16x16x32 bf16. BM=64, full N=128, K=128.
// LDS rows padded to 136 elems (272B = 17*16B) -> 2-way bank max on b128 reads.
__global__ __launch_bounds__(256) void vgemm_kernel(
    const float* __restrict__ z, const __hip_bfloat16* __restrict__ Wvt,
    __hip_bfloat16* __restrict__ Vb) {
  __shared__ __hip_bfloat16 zb[64 * 136];
  __shared__ __hip_bfloat16 wv[128 * 136];
  int tid = threadIdx.x;
  size_t row0 = (size_t)blockIdx.x * 64;
  for (int n = 0; n < 8; ++n) {
    int flat = n * 1024 + tid * 4;       // 0..8191 f32
    int r = flat >> 7, c = flat & 127;
    float4 v = *(const float4*)&z[(row0 + r) * NE + c];
    uint2 u = {pk2(v.x, v.y), pk2(v.z, v.w)};
    *(uint2*)&zb[r * 136 + c] = u;
  }
  const short* Wg = (const short*)Wvt;
  short* wl = (short*)wv;
  for (int n = 0; n < 8; ++n) {
    int chunk = n * 256 + tid;           // 0..2047 x 16B
    int r = chunk >> 4, c16 = chunk & 15;
    short8v v = *(const short8v*)&Wg[r * NE + c16 * 8];
    *(short8v*)&wl[r * 136 + c16 * 8] = v;
  }
  __syncthreads();
  int wid = tid >> 6, l = tid & 63;
  int lr = l & 15, lk = l >> 4;
  const short* zl = (const short*)zb;
  float4v acc[4][2] = {};
  short8v bfrag[2][4];
#pragma unroll
  for (int ct = 0; ct < 2; ++ct) {
    int col = (wid * 2 + ct) * 16 + lr;
#pragma unroll
    for (int ks = 0; ks < 4; ++ks)
      bfrag[ct][ks] = *(const short8v*)&wl[col * 136 + ks * 32 + lk * 8];
  }
#pragma unroll
  for (int ks = 0; ks < 4; ++ks)
#pragma unroll
    for (int st = 0; st < 4; ++st) {
      short8v a = *(const short8v*)&zl[(st * 16 + lr) * 136 + ks * 32 + lk * 8];
      acc[st][0] = __builtin_amdgcn_mfma_f32_16x16x32_bf16(a, bfrag[0][ks], acc[st][0], 0, 0, 0);
      acc[st][1] = __builtin_amdgcn_mfma_f32_16x16x32_bf16(a, bfrag[1][ks], acc[st][1], 0, 0, 0);
    }
#pragma unroll
  for (int st = 0; st < 4; ++st)
#pragma unroll
    for (int ct = 0; ct < 2; ++ct)
#pragma unroll
      for (int r = 0; r < 4; ++r) {
        size_t row = row0 + st * 16 + lk * 4 + r;
        int col = (wid * 2 + ct) * 16 + lr;
        Vb[row * NE + col] = __float2bfloat16(acc[st][ct][r]);
      }
}

// one wave per cell (4/block): softmax over [points, fake] then PV gather
__global__ __launch_bounds__(256) void attn3_kernel(
    const __hip_bfloat16* __restrict__ Vb, const float* __restrict__ S,
    const float* __restrict__ FS, const float* __restrict__ fakeKV,
    const int* __restrict__ counts, const unsigned short* __restrict__ lists,
    float* __restrict__ out) {
  int w = threadIdx.x >> 6, l = threadIdx.x & 63;
  int cell = blockIdx.x * 4 + w;
  int s = cell & (NS - 1);
  __shared__ float sc[4][24][8];
  __shared__ unsigned short pl[4][24];
  int cnt = min(counts[cell], CAP);
  if (l < cnt) {
    int pid = lists[cell * CAP + l];
    pl[w][l] = (unsigned short)pid;
    float4 a = *(const float4*)&S[(size_t)pid * 8];
    float4 b = *(const float4*)&S[(size_t)pid * 8 + 4];
    sc[w][l][0] = a.x; sc[w][l][1] = a.y; sc[w][l][2] = a.z; sc[w][l][3] = a.w;
    sc[w][l][4] = b.x; sc[w][l][5] = b.y; sc[w][l][6] = b.z; sc[w][l][7] = b.w;
  } else if (l == cnt) {
#pragma unroll
    for (int h = 0; h < 8; ++h) sc[w][l][h] = FS[(size_t)s * 8 + h];
  }
  __syncthreads();
  if (l < 8) {
    int T = cnt + 1;
    float m = -1e30f;
    for (int t = 0; t < T; ++t) m = fmaxf(m, sc[w][t][l]);
    float sum = 0.f;
    for (int t = 0; t < T; ++t) {
      float e = __expf(sc[w][t][l] - m);
      sum += e;
      sc[w][t][l] = e;
    }
    float inv = 1.f / sum;
    for (int t = 0; t < T; ++t) sc[w][t][l] *= inv;
  }
  __syncthreads();
  int h0 = l >> 4, h1 = 4 + h0;
  float acc0 = 0.f, acc1 = 0.f;
  for (int t = 0; t < cnt; ++t) {
    int pid = pl[w][t];
    acc0 += sc[w][t][h0] * __bfloat162float(Vb[(size_t)pid * NE + l]);
    acc1 += sc[w][t][h1] * __bfloat162float(Vb[(size_t)pid * NE + 64 + l]);
  }
  acc0 += sc[w][cnt][h0] * fakeKV[NE + l];
  acc1 += sc[w][cnt][h1] * fakeKV[NE + 64 + l];
  out[(size_t)OUT0 + (size_t)cell * NE + l] = acc0;
  out[(size_t)OUT0 + (size_t)cell * NE + 64 + l] = acc1;
}

// in-place: out_rows = O_rows @ Wo ; 64 rows per block
__global__ __launch_bounds__(256) void wo_gemm(
    const float* __restrict__ Wo, float* __restrict__ out) {
  __shared__ float Os[64][132];
  int blk = blockIdx.x;
  int tid = threadIdx.x;
  float* base = out + (size_t)OUT0 + (size_t)blk * 64 * NE;
  {
    int k4 = tid & 31, r0 = tid >> 5;
    for (int rr = r0; rr < 64; rr += 8) {
      float4 v = *(const float4*)&base[(size_t)rr * NE + k4 * 4];
      *(float4*)&Os[rr][k4 * 4] = v;
    }
  }
  __syncthreads();
  int tx = tid & 15, ty = tid >> 4;
  float acc[4][8] = {{0.f}};
  for (int k = 0; k < NE; ++k) {
    float b8[8];
    *(float4*)&b8[0] = *(const float4*)&Wo[k * NE + tx * 8];
    *(float4*)&b8[4] = *(const float4*)&Wo[k * NE + tx * 8 + 4];
#pragma unroll
    for (int i = 0; i < 4; ++i) {
      float a = Os[ty * 4 + i][k];
#pragma unroll
      for (int j = 0; j < 8; ++j) acc[i][j] += a * b8[j];
    }
  }
#pragma unroll
  for (int i = 0; i < 4; ++i)
#pragma unroll
    for (int j = 0; j < 8; ++j)
      base[(size_t)(ty * 4 + i) * NE + tx * 8 + j] = acc[i][j];
}

extern "C" void kernel_launch(void* const* d_in, const int* in_sizes, int n_in,
                              void* d_out, int out_size, void* d_ws, size_t ws_size,
                              hipStream_t stream) {
  const float* xc_off  = (const float*)d_in[0];
  const float* xc_on   = (const float*)d_in[1];
  const float* zc_off  = (const float*)d_in[2];
  const float* latents = (const float*)d_in[4];
  const float* fake    = (const float*)d_in[5];
  const float* Wq      = (const float*)d_in[6];
  const float* Wk      = (const float*)d_in[7];
  const float* Wv      = (const float*)d_in[8];
  const float* Wo      = (const float*)d_in[9];
  float* out = (float*)d_out;

  char* ws = (char*)d_ws;
  int*            counts = (int*)(ws);
  unsigned short* lists  = (unsigned short*)(ws + 131072);
  float*          S      = (float*)(ws + 1441792);
  __hip_bfloat16* G      = (__hip_bfloat16*)(ws + 3538944);
  float*          FS     = (float*)(ws + 11927552);
  float*          fakeKV = (float*)(ws + 12058624);
  __hip_bfloat16* Wvt    = (__hip_bfloat16*)(ws + 12059648);
  __hip_bfloat16* Vb     = (__hip_bfloat16*)(ws + 12092416);
  unsigned short* ps     = (unsigned short*)(ws + 28869632);

  hipMemsetAsync(counts, 0, 131072, stream);
  hipLaunchKernelGGL(nearest_kernel, dim3(NPTS / 256), dim3(256), 0, stream,
                     xc_off, xc_on, counts, lists, ps);
  hipLaunchKernelGGL(copy0_kernel, dim3(OUT0 / 256), dim3(256), 0, stream, xc_on, out);
  hipLaunchKernelGGL(tiny_prep, dim3(1), dim3(256), 0, stream,
                     fake, Wk, Wv, fakeKV, Wvt);
  hipLaunchKernelGGL(prep_kernel, dim3(NS / 8), dim3(256), 0, stream,
                     latents, Wq, Wk, fakeKV, G, FS);
  hipLaunchKernelGGL(scores_kernel, dim3(NPTS / 4), dim3(256), 0, stream,
                     zc_off, ps, G, S);
  hipLaunchKernelGGL(vgemm_kernel, dim3(NPTS / 64), dim3(256), 0, stream,
                     zc_off, Wvt, Vb);
  hipLaunchKernelGGL(attn3_kernel, dim3(NCELL / 4), dim3(256), 0, stream,
                     Vb, S, FS, fakeKV, counts, lists, out);
  hipLaunchKernelGGL(wo_gemm, dim3(NCELL / 64), dim3(256), 0, stream, Wo, out);
}

// Round 6
// 112.017 us; speedup vs baseline: 3.6197x; 1.2324x over previous
//
#include <hip/hip_runtime.h>
#include <hip/hip_bf16.h>

#define NB 8
#define NU 8192
#define GN0 64
#define GN1 64
#define NS 4096
#define NE 128
#define NH 8
#define CAP 20
#define NPTS (NB * NU)               // 65536
#define NCELL (NB * NS)              // 32768
#define OUT0 (NB * GN0 * GN1 * 2)    // 65536 f32 passthrough

// ---------------------------------------------------------------------------
// ws layout (bytes), total ~27.8 MB:
//   counts @ 0        (131072)   int32 per cell (zeroed by copy0_kernel)
//   lists  @ 131072   (1310720)  u16 point ids per cell
//   S      @ 1441792  (2097152)  f32 scores [NPTS][8] (pre-scaled by 0.25)
//   G      @ 3538944  (8388608)  bf16 [NS][8][128]: Wk_h @ q_{s,h}
//   FS     @ 11927552 (131072)   f32 [NS][8] fake-token scores (pre-scaled)
//   fakeKV @ 12058624 (1024)     f32 fakeK[128], fakeV[128]
//   Wvt    @ 12059648 (32768)    bf16 Wv^T [col][k]
//   Wot    @ 12092416 (32768)    bf16 Wo^T [col][k]
//   Vb     @ 12125184 (16777216) bf16 V = Z @ Wv
//   ps     @ 28902400 (131072)   u16 per-point s-index
// ---------------------------------------------------------------------------

typedef __attribute__((ext_vector_type(8))) short short8v;
typedef __attribute__((ext_vector_type(4))) float float4v;

static __device__ inline unsigned pk2(float a, float b) {
  __hip_bfloat16 x = __float2bfloat16(a), y = __float2bfloat16(b);
  return ((unsigned)*(unsigned short*)&y << 16) | *(unsigned short*)&x;
}

// copy xc_on -> out[0:OUT0]  AND zero the counts array (replaces memset:
// rocclr fillBuffer cost 39us/replay in-graph)
__global__ __launch_bounds__(256) void copy0_kernel(
    const float* __restrict__ xc_on, float* __restrict__ out,
    int* __restrict__ counts) {
  int i = blockIdx.x * blockDim.x + threadIdx.x;
  out[i] = xc_on[i];
  if (i < NCELL) counts[i] = 0;
}

__global__ __launch_bounds__(256) void nearest_kernel(
    const float* __restrict__ xc_off, const float* __restrict__ xc_on,
    int* __restrict__ counts, unsigned short* __restrict__ lists,
    unsigned short* __restrict__ ps) {
  int idx = blockIdx.x * blockDim.x + threadIdx.x;
  if (idx >= NPTS) return;
  int b = idx >> 13;
  const float* g = xc_on + (size_t)b * (GN0 * GN1 * 2);
  float c00 = g[0], c01 = g[GN1 * 2], c10 = g[1], c11 = g[3];
  float x0 = xc_off[(size_t)idx * 2 + 0];
  float x1 = xc_off[(size_t)idx * 2 + 1];
  float f0 = rintf((x0 - c00) / (c01 - c00));   // np.round = RNE
  float f1 = rintf((x1 - c10) / (c11 - c10));
  int i0 = (int)fminf(fmaxf(f0, 0.f), 63.f);
  int i1 = (int)fminf(fmaxf(f1, 0.f), 63.f);
  int s = i0 * GN1 + i1;
  ps[idx] = (unsigned short)s;
  int cell = b * NS + s;
  int pos = atomicAdd(&counts[cell], 1);
  if (pos < CAP) lists[cell * CAP + pos] = (unsigned short)idx;
}

// block 0: fake K/V rows; blocks 1..64: Wv^T / Wo^T bf16 transposes
__global__ __launch_bounds__(256) void tiny_prep(
    const float* __restrict__ fake, const float* __restrict__ Wk,
    const float* __restrict__ Wv, const float* __restrict__ Wo,
    float* __restrict__ fakeKV, __hip_bfloat16* __restrict__ Wvt,
    __hip_bfloat16* __restrict__ Wot) {
  int t = threadIdx.x;
  if (blockIdx.x == 0) {
    __shared__ float frow[NE];
    if (t < NE) frow[t] = fake[t];
    __syncthreads();
    int e = t & 127, half = t >> 7;
    const float* W = half ? Wv : Wk;
    float acc = 0.f;
    for (int j = 0; j < NE; ++j) acc += frow[j] * W[j * NE + e];
    fakeKV[half * NE + e] = acc;
  } else {
    int flat = (blockIdx.x - 1) * 256 + t;   // 0..16383
    int j = flat >> 7, e = flat & 127;
    Wvt[e * NE + j] = __float2bfloat16(Wv[flat]);
    Wot[e * NE + j] = __float2bfloat16(Wo[flat]);
  }
}

// per 8 latent rows: q = latent @ Wq (kept in LDS), then G[s][h][:] and FS
__global__ __launch_bounds__(256) void prep_kernel(
    const float* __restrict__ latents, const float* __restrict__ Wq,
    const float* __restrict__ Wk, const float* __restrict__ fakeKV,
    __hip_bfloat16* __restrict__ G, float* __restrict__ FS) {
  int s0 = blockIdx.x * 8;
  int tid = threadIdx.x;
  __shared__ float lrow[8][NE];
  __shared__ float qs[8][NE];
  for (int i = tid; i < 8 * NE; i += 256)
    lrow[i >> 7][i & 127] = latents[(size_t)s0 * NE + i];
  __syncthreads();
  for (int i = tid; i < 8 * NE; i += 256) {
    int sl = i >> 7, e = i & 127;
    float acc = 0.f;
    for (int j = 0; j < NE; ++j) acc += lrow[sl][j] * Wq[j * NE + e];
    qs[sl][e] = acc;
  }
  __syncthreads();
  int j = tid & 127, half = tid >> 7;
  for (int hh = 0; hh < 4; ++hh) {
    int h = half * 4 + hh;
    float wkr[16];
#pragma unroll
    for (int d = 0; d < 16; ++d) wkr[d] = Wk[j * NE + h * 16 + d];
    for (int sl = 0; sl < 8; ++sl) {
      float acc = 0.f;
#pragma unroll
      for (int d = 0; d < 16; ++d) acc += wkr[d] * qs[sl][h * 16 + d];
      G[((size_t)(s0 + sl) * 8 + h) * NE + j] = __float2bfloat16(acc);
    }
  }
  if (tid < 64) {
    int sl = tid >> 3, h = tid & 7;
    float acc = 0.f;
#pragma unroll
    for (int d = 0; d < 16; ++d) acc += qs[sl][h * 16 + d] * fakeKV[h * 16 + d];
    FS[(size_t)(s0 + sl) * 8 + h] = acc * 0.25f;
  }
}

// one wave per point: 8 head scores via z . G[s,h], butterfly reduce
__global__ __launch_bounds__(256) void scores_kernel(
    const float* __restrict__ z, const unsigned short* __restrict__ ps,
    const __hip_bfloat16* __restrict__ G, float* __restrict__ S) {
  int p = blockIdx.x * 4 + (threadIdx.x >> 6);
  int l = threadIdx.x & 63;
  int s = ps[p];
  float z0 = z[(size_t)p * NE + l], z1 = z[(size_t)p * NE + 64 + l];
  const __hip_bfloat16* g = G + (size_t)s * (8 * NE);
  float ph[8];
#pragma unroll
  for (int h = 0; h < 8; ++h) {
    float g0 = __bfloat162float(g[h * NE + l]);
    float g1 = __bfloat162float(g[h * NE + 64 + l]);
    ph[h] = z0 * g0 + z1 * g1;
  }
#pragma unroll
  for (int h = 0; h < 8; ++h)
#pragma unroll
    for (int off = 32; off; off >>= 1) ph[h] += __shfl_xor(ph[h], off);
  if (l == 0) {
    float4 a = {ph[0] * 0.25f, ph[1] * 0.25f, ph[2] * 0.25f, ph[3] * 0.25f};
    float4 b = {ph[4] * 0.25f, ph[5] * 0.25f, ph[6] * 0.25f, ph[7] * 0.25f};
    *(float4*)&S[(size_t)p * 8] = a;
    *(float4*)&S[(size_t)p * 8 + 4] = b;
  }
}

// V = bf16(Z @ Wv) via MFMA 16x16x32 bf16. BM=64, N=128, K=128.
__global__ __launch_bounds__(256) void vgemm_kernel(
    const float* __restrict__ z, const __hip_bfloat16* __restrict__ Wvt,
    __hip_bfloat16* __restrict__ Vb) {
  __shared__ __hip_bfloat16 zb[64 * 136];
  __shared__ __hip_bfloat16 wv[128 * 136];
  int tid = threadIdx.x;
  size_t row0 = (size_t)blockIdx.x * 64;
  for (int n = 0; n < 8; ++n) {
    int flat = n * 1024 + tid * 4;       // 0..8191 f32
    int r = flat >> 7, c = flat & 127;
    float4 v = *(const float4*)&z[(row0 + r) * NE + c];
    uint2 u = {pk2(v.x, v.y), pk2(v.z, v.w)};
    *(uint2*)&zb[r * 136 + c] = u;
  }
  const short* Wg = (const short*)Wvt;
  short* wl = (short*)wv;
  for (int n = 0; n < 8; ++n) {
    int chunk = n * 256 + tid;           // 0..2047 x 16B
    int r = chunk >> 4, c16 = chunk & 15;
    short8v v = *(const short8v*)&Wg[r * NE + c16 * 8];
    *(short8v*)&wl[r * 136 + c16 * 8] = v;
  }
  __syncthreads();
  int wid = tid >> 6, l = tid & 63;
  int lr = l & 15, lk = l >> 4;
  const short* zl = (const short*)zb;
  float4v acc[4][2] = {};
  short8v bfrag[2][4];
#pragma unroll
  for (int ct = 0; ct < 2; ++ct) {
    int col = (wid * 2 + ct) * 16 + lr;
#pragma unroll
    for (int ks = 0; ks < 4; ++ks)
      bfrag[ct][ks] = *(const short8v*)&wl[col * 136 + ks * 32 + lk * 8];
  }
#pragma unroll
  for (int ks = 0; ks < 4; ++ks)
#pragma unroll
    for (int st = 0; st < 4; ++st) {
      short8v a = *(const short8v*)&zl[(st * 16 + lr) * 136 + ks * 32 + lk * 8];
      acc[st][0] = __builtin_amdgcn_mfma_f32_16x16x32_bf16(a, bfrag[0][ks], acc[st][0], 0, 0, 0);
      acc[st][1] = __builtin_amdgcn_mfma_f32_16x16x32_bf16(a, bfrag[1][ks], acc[st][1], 0, 0, 0);
    }
#pragma unroll
  for (int st = 0; st < 4; ++st)
#pragma unroll
    for (int ct = 0; ct < 2; ++ct)
#pragma unroll
      for (int r = 0; r < 4; ++r) {
        size_t row = row0 + st * 16 + lk * 4 + r;
        int col = (wid * 2 + ct) * 16 + lr;
        Vb[row * NE + col] = __float2bfloat16(acc[st][ct][r]);
      }
}

// one wave per cell (4/block): softmax over [points, fake] then PV gather
__global__ __launch_bounds__(256) void attn3_kernel(
    const __hip_bfloat16* __restrict__ Vb, const float* __restrict__ S,
    const float* __restrict__ FS, const float* __restrict__ fakeKV,
    const int* __restrict__ counts, const unsigned short* __restrict__ lists,
    float* __restrict__ out) {
  int w = threadIdx.x >> 6, l = threadIdx.x & 63;
  int cell = blockIdx.x * 4 + w;
  int s = cell & (NS - 1);
  __shared__ float sc[4][24][8];
  __shared__ unsigned short pl[4][24];
  int cnt = min(counts[cell], CAP);
  if (l < cnt) {
    int pid = lists[cell * CAP + l];
    pl[w][l] = (unsigned short)pid;
    float4 a = *(const float4*)&S[(size_t)pid * 8];
    float4 b = *(const float4*)&S[(size_t)pid * 8 + 4];
    sc[w][l][0] = a.x; sc[w][l][1] = a.y; sc[w][l][2] = a.z; sc[w][l][3] = a.w;
    sc[w][l][4] = b.x; sc[w][l][5] = b.y; sc[w][l][6] = b.z; sc[w][l][7] = b.w;
  } else if (l == cnt) {
#pragma unroll
    for (int h = 0; h < 8; ++h) sc[w][l][h] = FS[(size_t)s * 8 + h];
  }
  __syncthreads();
  if (l < 8) {
    int T = cnt + 1;
    float m = -1e30f;
    for (int t = 0; t < T; ++t) m = fmaxf(m, sc[w][t][l]);
    float sum = 0.f;
    for (int t = 0; t < T; ++t) {
      float e = __expf(sc[w][t][l] - m);
      sum += e;
      sc[w][t][l] = e;
    }
    float inv = 1.f / sum;
    for (int t = 0; t < T; ++t) sc[w][t][l] *= inv;
  }
  __syncthreads();
  int h0 = l >> 4, h1 = 4 + h0;
  float acc0 = 0.f, acc1 = 0.f;
  for (int t = 0; t < cnt; ++t) {
    int pid = pl[w][t];
    acc0 += sc[w][t][h0] * __bfloat162float(Vb[(size_t)pid * NE + l]);
    acc1 += sc[w][t][h1] * __bfloat162float(Vb[(size_t)pid * NE + 64 + l]);
  }
  acc0 += sc[w][cnt][h0] * fakeKV[NE + l];
  acc1 += sc[w][cnt][h1] * fakeKV[NE + 64 + l];
  out[(size_t)OUT0 + (size_t)cell * NE + l] = acc0;
  out[(size_t)OUT0 + (size_t)cell * NE + 64 + l] = acc1;
}

// in-place MFMA: out_rows = O_rows @ Wo (O -> bf16, Wot staged bf16)
__global__ __launch_bounds__(256) void wo_mfma(
    const __hip_bfloat16* __restrict__ Wot, float* __restrict__ out) {
  __shared__ __hip_bfloat16 ob[64 * 136];
  __shared__ __hip_bfloat16 wo[128 * 136];
  int tid = threadIdx.x;
  float* base = out + (size_t)OUT0 + (size_t)blockIdx.x * 64 * NE;
  for (int n = 0; n < 8; ++n) {
    int flat = n * 1024 + tid * 4;
    int r = flat >> 7, c = flat & 127;
    float4 v = *(const float4*)&base[(size_t)r * NE + c];
    uint2 u = {pk2(v.x, v.y), pk2(v.z, v.w)};
    *(uint2*)&ob[r * 136 + c] = u;
  }
  const short* Wg = (const short*)Wot;
  short* wl = (short*)wo;
  for (int n = 0; n < 8; ++n) {
    int chunk = n * 256 + tid;
    int r = chunk >> 4, c16 = chunk & 15;
    short8v v = *(const short8v*)&Wg[r * NE + c16 * 8];
    *(short8v*)&wl[r * 136 + c16 * 8] = v;
  }
  __syncthreads();
  int wid = tid >> 6, l = tid & 63;
  int lr = l & 15, lk = l >> 4;
  const short* ol = (const short*)ob;
  float4v acc[4][2] = {};
  short8v bfrag[2][4];
#pragma unroll
  for (int ct = 0; ct < 2; ++ct) {
    int col = (wid * 2 + ct) * 16 + lr;
#pragma unroll
    for (int ks = 0; ks < 4; ++ks)
      bfrag[ct][ks] = *(const short8v*)&wl[col * 136 + ks * 32 + lk * 8];
  }
#pragma unroll
  for (int ks = 0; ks < 4; ++ks)
#pragma unroll
    for (int st = 0; st < 4; ++st) {
      short8v a = *(const short8v*)&ol[(st * 16 + lr) * 136 + ks * 32 + lk * 8];
      acc[st][0] = __builtin_amdgcn_mfma_f32_16x16x32_bf16(a, bfrag[0][ks], acc[st][0], 0, 0, 0);
      acc[st][1] = __builtin_amdgcn_mfma_f32_16x16x32_bf16(a, bfrag[1][ks], acc[st][1], 0, 0, 0);
    }
#pragma unroll
  for (int st = 0; st < 4; ++st)
#pragma unroll
    for (int ct = 0; ct < 2; ++ct)
#pragma unroll
      for (int r = 0; r < 4; ++r) {
        int row = st * 16 + lk * 4 + r;
        int col = (wid * 2 + ct) * 16 + lr;
        base[(size_t)row * NE + col] = acc[st][ct][r];
      }
}

extern "C" void kernel_launch(void* const* d_in, const int* in_sizes, int n_in,
                              void* d_out, int out_size, void* d_ws, size_t ws_size,
                              hipStream_t stream) {
  const float* xc_off  = (const float*)d_in[0];
  const float* xc_on   = (const float*)d_in[1];
  const float* zc_off  = (const float*)d_in[2];
  const float* latents = (const float*)d_in[4];
  const float* fake    = (const float*)d_in[5];
  const float* Wq      = (const float*)d_in[6];
  const float* Wk      = (const float*)d_in[7];
  const float* Wv      = (const float*)d_in[8];
  const float* Wo      = (const float*)d_in[9];
  float* out = (float*)d_out;

  char* ws = (char*)d_ws;
  int*            counts = (int*)(ws);
  unsigned short* lists  = (unsigned short*)(ws + 131072);
  float*          S      = (float*)(ws + 1441792);
  __hip_bfloat16* G      = (__hip_bfloat16*)(ws + 3538944);
  float*          FS     = (float*)(ws + 11927552);
  float*          fakeKV = (float*)(ws + 12058624);
  __hip_bfloat16* Wvt    = (__hip_bfloat16*)(ws + 12059648);
  __hip_bfloat16* Wot    = (__hip_bfloat16*)(ws + 12092416);
  __hip_bfloat16* Vb     = (__hip_bfloat16*)(ws + 12125184);
  unsigned short* ps     = (unsigned short*)(ws + 28902400);

  hipLaunchKernelGGL(copy0_kernel, dim3(OUT0 / 256), dim3(256), 0, stream,
                     xc_on, out, counts);
  hipLaunchKernelGGL(nearest_kernel, dim3(NPTS / 256), dim3(256), 0, stream,
                     xc_off, xc_on, counts, lists, ps);
  hipLaunchKernelGGL(tiny_prep, dim3(65), dim3(256), 0, stream,
                     fake, Wk, Wv, Wo, fakeKV, Wvt, Wot);
  hipLaunchKernelGGL(prep_kernel, dim3(NS / 8), dim3(256), 0, stream,
                     latents, Wq, Wk, fakeKV, G, FS);
  hipLaunchKernelGGL(scores_kernel, dim3(NPTS / 4), dim3(256), 0, stream,
                     zc_off, ps, G, S);
  hipLaunchKernelGGL(vgemm_kernel, dim3(NPTS / 64), dim3(256), 0, stream,
                     zc_off, Wvt, Vb);
  hipLaunchKernelGGL(attn3_kernel, dim3(NCELL / 4), dim3(256), 0, stream,
                     Vb, S, FS, fakeKV, counts, lists, out);
  hipLaunchKernelGGL(wo_mfma, dim3(NCELL / 64), dim3(256), 0, stream, Wot, out);
}

// Round 7
// 89.407 us; speedup vs baseline: 4.5351x; 1.2529x over previous
//
#include <hip/hip_runtime.h>
#include <hip/hip_bf16.h>

#define NB 8
#define NU 8192
#define GN0 64
#define GN1 64
#define NS 4096
#define NE 128
#define NH 8
#define CAP 20
#define NPTS (NB * NU)               // 65536
#define NCELL (NB * NS)              // 32768
#define OUT0 (NB * GN0 * GN1 * 2)    // 65536 f32 passthrough

// ---------------------------------------------------------------------------
// ws layout (bytes), total ~27.8 MB:
//   counts @ 0        (131072)   int32 per cell (zeroed by setup_kernel)
//   lists  @ 131072   (1310720)  u16 point ids per cell
//   S      @ 1441792  (2097152)  f32 scores [NPTS][8] (pre-scaled by 0.25)
//   G      @ 3538944  (8388608)  bf16 [NS][8][128]: Wk_h @ q_{s,h}
//   FS     @ 11927552 (131072)   f32 [NS][8] fake-token scores (pre-scaled)
//   fakeKV @ 12058624 (1024)     f32 fakeK[128], fakeV[128]
//   Wvt    @ 12059648 (32768)    bf16 Wv^T [col][k]
//   Wot    @ 12092416 (32768)    bf16 Wo^T [col][k]
//   Vb     @ 12125184 (16777216) bf16 V = Z @ Wv
//   ps     @ 28902400 (131072)   u16 per-point s-index
// ---------------------------------------------------------------------------

typedef __attribute__((ext_vector_type(8))) short short8v;
typedef __attribute__((ext_vector_type(4))) float float4v;

static __device__ inline unsigned pk2(float a, float b) {
  __hip_bfloat16 x = __float2bfloat16(a), y = __float2bfloat16(b);
  return ((unsigned)*(unsigned short*)&y << 16) | *(unsigned short*)&x;
}
static __device__ inline float bfs(short v) {
  unsigned u = (unsigned)(unsigned short)v << 16;
  return __builtin_bit_cast(float, u);
}

// fused: out0 passthrough + counts zero + fakeKV row + Wv^T/Wo^T bf16 staging
__global__ __launch_bounds__(256) void setup_kernel(
    const float* __restrict__ xc_on, const float* __restrict__ fake,
    const float* __restrict__ Wk, const float* __restrict__ Wv,
    const float* __restrict__ Wo,
    float* __restrict__ out, int* __restrict__ counts,
    float* __restrict__ fakeKV, __hip_bfloat16* __restrict__ Wvt,
    __hip_bfloat16* __restrict__ Wot) {
  int t = threadIdx.x;
  int i = blockIdx.x * 256 + t;
  out[i] = xc_on[i];                 // grid = OUT0/256, exact
  if (i < NCELL) counts[i] = 0;
  if (blockIdx.x == 0) {
    __shared__ float frow[NE];
    if (t < NE) frow[t] = fake[t];
    __syncthreads();
    int e = t & 127, half = t >> 7;
    const float* W = half ? Wv : Wk;
    float acc = 0.f;
    for (int j = 0; j < NE; ++j) acc += frow[j] * W[j * NE + e];
    fakeKV[half * NE + e] = acc;
  } else if (blockIdx.x <= 64) {
    int flat = (blockIdx.x - 1) * 256 + t;   // 0..16383
    int j = flat >> 7, e = flat & 127;
    Wvt[e * NE + j] = __float2bfloat16(Wv[flat]);
    Wot[e * NE + j] = __float2bfloat16(Wo[flat]);
  }
}

__global__ __launch_bounds__(256) void nearest_kernel(
    const float* __restrict__ xc_off, const float* __restrict__ xc_on,
    int* __restrict__ counts, unsigned short* __restrict__ lists,
    unsigned short* __restrict__ ps) {
  int idx = blockIdx.x * blockDim.x + threadIdx.x;
  if (idx >= NPTS) return;
  int b = idx >> 13;
  const float* g = xc_on + (size_t)b * (GN0 * GN1 * 2);
  float c00 = g[0], c01 = g[GN1 * 2], c10 = g[1], c11 = g[3];
  float x0 = xc_off[(size_t)idx * 2 + 0];
  float x1 = xc_off[(size_t)idx * 2 + 1];
  float f0 = rintf((x0 - c00) / (c01 - c00));   // np.round = RNE
  float f1 = rintf((x1 - c10) / (c11 - c10));
  int i0 = (int)fminf(fmaxf(f0, 0.f), 63.f);
  int i1 = (int)fminf(fmaxf(f1, 0.f), 63.f);
  int s = i0 * GN1 + i1;
  ps[idx] = (unsigned short)s;
  int cell = b * NS + s;
  int pos = atomicAdd(&counts[cell], 1);
  if (pos < CAP) lists[cell * CAP + pos] = (unsigned short)idx;
}

// per 8 latent rows: q = latent @ Wq (kept in LDS), then G[s][h][:] and FS
__global__ __launch_bounds__(256) void prep_kernel(
    const float* __restrict__ latents, const float* __restrict__ Wq,
    const float* __restrict__ Wk, const float* __restrict__ fakeKV,
    __hip_bfloat16* __restrict__ G, float* __restrict__ FS) {
  int s0 = blockIdx.x * 8;
  int tid = threadIdx.x;
  __shared__ float lrow[8][NE];
  __shared__ float qs[8][NE];
  for (int i = tid; i < 8 * NE; i += 256)
    lrow[i >> 7][i & 127] = latents[(size_t)s0 * NE + i];
  __syncthreads();
  for (int i = tid; i < 8 * NE; i += 256) {
    int sl = i >> 7, e = i & 127;
    float acc = 0.f;
    for (int j = 0; j < NE; ++j) acc += lrow[sl][j] * Wq[j * NE + e];
    qs[sl][e] = acc;
  }
  __syncthreads();
  int j = tid & 127, half = tid >> 7;
  for (int hh = 0; hh < 4; ++hh) {
    int h = half * 4 + hh;
    float wkr[16];
#pragma unroll
    for (int d = 0; d < 16; ++d) wkr[d] = Wk[j * NE + h * 16 + d];
    for (int sl = 0; sl < 8; ++sl) {
      float acc = 0.f;
#pragma unroll
      for (int d = 0; d < 16; ++d) acc += wkr[d] * qs[sl][h * 16 + d];
      G[((size_t)(s0 + sl) * 8 + h) * NE + j] = __float2bfloat16(acc);
    }
  }
  if (tid < 64) {
    int sl = tid >> 3, h = tid & 7;
    float acc = 0.f;
#pragma unroll
    for (int d = 0; d < 16; ++d) acc += qs[sl][h * 16 + d] * fakeKV[h * 16 + d];
    FS[(size_t)(s0 + sl) * 8 + h] = acc * 0.25f;
  }
}

// one wave per point; G row read as 2x16B/lane; 16-lane-group reduce (8 shfls)
__global__ __launch_bounds__(256) void scores_kernel(
    const float* __restrict__ z, const unsigned short* __restrict__ ps,
    const __hip_bfloat16* __restrict__ G, float* __restrict__ S) {
  int p = blockIdx.x * 4 + (threadIdx.x >> 6);
  int l = threadIdx.x & 63;
  int s = ps[p];
  const short8v* g8 = (const short8v*)(G + (size_t)s * (8 * NE));
  short8v ga = g8[l];        // head l>>4, d = (l&15)*8 + j
  short8v gb = g8[64 + l];   // head 4 + (l>>4), same d
  const float* zp = z + (size_t)p * NE + (l & 15) * 8;
  float4 za = *(const float4*)zp;
  float4 zb = *(const float4*)(zp + 4);
  float zv[8] = {za.x, za.y, za.z, za.w, zb.x, zb.y, zb.z, zb.w};
  float pa = 0.f, pb = 0.f;
#pragma unroll
  for (int j = 0; j < 8; ++j) {
    pa += zv[j] * bfs(ga[j]);
    pb += zv[j] * bfs(gb[j]);
  }
#pragma unroll
  for (int off = 1; off < 16; off <<= 1) {
    pa += __shfl_xor(pa, off);
    pb += __shfl_xor(pb, off);
  }
  if ((l & 15) == 0) {
    S[(size_t)p * 8 + (l >> 4)] = pa * 0.25f;
    S[(size_t)p * 8 + 4 + (l >> 4)] = pb * 0.25f;
  }
}

// V = bf16(Z @ Wv) via MFMA 16x16x32 bf16. BM=64, N=128, K=128.
__global__ __launch_bounds__(256) void vgemm_kernel(
    const float* __restrict__ z, const __hip_bfloat16* __restrict__ Wvt,
    __hip_bfloat16* __restrict__ Vb) {
  __shared__ __hip_bfloat16 zb[64 * 136];
  __shared__ __hip_bfloat16 wv[128 * 136];
  int tid = threadIdx.x;
  size_t row0 = (size_t)blockIdx.x * 64;
  for (int n = 0; n < 8; ++n) {
    int flat = n * 1024 + tid * 4;       // 0..8191 f32
    int r = flat >> 7, c = flat & 127;
    float4 v = *(const float4*)&z[(row0 + r) * NE + c];
    uint2 u = {pk2(v.x, v.y), pk2(v.z, v.w)};
    *(uint2*)&zb[r * 136 + c] = u;
  }
  const short* Wg = (const short*)Wvt;
  short* wl = (short*)wv;
  for (int n = 0; n < 8; ++n) {
    int chunk = n * 256 + tid;           // 0..2047 x 16B
    int r = chunk >> 4, c16 = chunk & 15;
    short8v v = *(const short8v*)&Wg[r * NE + c16 * 8];
    *(short8v*)&wl[r * 136 + c16 * 8] = v;
  }
  __syncthreads();
  int wid = tid >> 6, l = tid & 63;
  int lr = l & 15, lk = l >> 4;
  const short* zl = (const short*)zb;
  float4v acc[4][2] = {};
  short8v bfrag[2][4];
#pragma unroll
  for (int ct = 0; ct < 2; ++ct) {
    int col = (wid * 2 + ct) * 16 + lr;
#pragma unroll
    for (int ks = 0; ks < 4; ++ks)
      bfrag[ct][ks] = *(const short8v*)&wl[col * 136 + ks * 32 + lk * 8];
  }
#pragma unroll
  for (int ks = 0; ks < 4; ++ks)
#pragma unroll
    for (int st = 0; st < 4; ++st) {
      short8v a = *(const short8v*)&zl[(st * 16 + lr) * 136 + ks * 32 + lk * 8];
      acc[st][0] = __builtin_amdgcn_mfma_f32_16x16x32_bf16(a, bfrag[0][ks], acc[st][0], 0, 0, 0);
      acc[st][1] = __builtin_amdgcn_mfma_f32_16x16x32_bf16(a, bfrag[1][ks], acc[st][1], 0, 0, 0);
    }
#pragma unroll
  for (int st = 0; st < 4; ++st)
#pragma unroll
    for (int ct = 0; ct < 2; ++ct)
#pragma unroll
      for (int r = 0; r < 4; ++r) {
        size_t row = row0 + st * 16 + lk * 4 + r;
        int col = (wid * 2 + ct) * 16 + lr;
        Vb[row * NE + col] = __float2bfloat16(acc[st][ct][r]);
      }
}

// fused attention + Wo: 64 cells/block, 16 waves; PV result goes straight to
// the LDS A-tile of the Wo MFMA (no O round-trip through memory).
__global__ __launch_bounds__(1024) void attn_wo_kernel(
    const __hip_bfloat16* __restrict__ Vb, const float* __restrict__ S,
    const float* __restrict__ FS, const float* __restrict__ fakeKV,
    const int* __restrict__ counts, const unsigned short* __restrict__ lists,
    const __hip_bfloat16* __restrict__ Wot, float* __restrict__ out) {
  __shared__ __hip_bfloat16 ob[64 * 136];   // O tile (bf16)
  __shared__ __hip_bfloat16 wo[128 * 136];  // Wo^T staged
  __shared__ float sc[16][24][8];
  __shared__ unsigned short pl[16][24];
  int tid = threadIdx.x, w = tid >> 6, l = tid & 63;
  // stage Wo^T (2 x 16B per thread); consumed only after the barrier below
  {
    const short* Wg = (const short*)Wot;
    short* wl = (short*)wo;
#pragma unroll
    for (int n = 0; n < 2; ++n) {
      int chunk = n * 1024 + tid;
      int r = chunk >> 4, c16 = chunk & 15;
      *(short8v*)&wl[r * 136 + c16 * 8] = *(const short8v*)&Wg[r * NE + c16 * 8];
    }
  }
  int cell0 = blockIdx.x * 64;
  for (int ci = 0; ci < 4; ++ci) {
    int row = w * 4 + ci;
    int cell = cell0 + row;
    int s = cell & (NS - 1);
    int cnt = min(counts[cell], CAP);
    if (l < cnt) {
      int pid = lists[cell * CAP + l];
      pl[w][l] = (unsigned short)pid;
      float4 a = *(const float4*)&S[(size_t)pid * 8];
      float4 b = *(const float4*)&S[(size_t)pid * 8 + 4];
      sc[w][l][0] = a.x; sc[w][l][1] = a.y; sc[w][l][2] = a.z; sc[w][l][3] = a.w;
      sc[w][l][4] = b.x; sc[w][l][5] = b.y; sc[w][l][6] = b.z; sc[w][l][7] = b.w;
    } else if (l == cnt) {
#pragma unroll
      for (int h = 0; h < 8; ++h) sc[w][l][h] = FS[(size_t)s * 8 + h];
    }
    __syncthreads();
    if (l < 8) {
      int T = cnt + 1;
      float m = -1e30f;
      for (int t = 0; t < T; ++t) m = fmaxf(m, sc[w][t][l]);
      float sum = 0.f;
      for (int t = 0; t < T; ++t) {
        float e = __expf(sc[w][t][l] - m);
        sum += e;
        sc[w][t][l] = e;
      }
      float inv = 1.f / sum;
      for (int t = 0; t < T; ++t) sc[w][t][l] *= inv;
    }
    __syncthreads();
    // PV: lane l covers d = 2l, 2l+1 (head l>>3); one dword V load per token
    int h = l >> 3;
    float acc0 = 0.f, acc1 = 0.f;
    for (int t = 0; t < cnt; ++t) {
      unsigned vv = ((const unsigned*)(Vb + (size_t)pl[w][t] * NE))[l];
      float wt = sc[w][t][h];
      acc0 += wt * bfs((short)(vv & 0xffff));
      acc1 += wt * bfs((short)(vv >> 16));
    }
    float2 fv = *(const float2*)&fakeKV[NE + 2 * l];
    float wt = sc[w][cnt][h];
    acc0 += wt * fv.x;
    acc1 += wt * fv.y;
    *(unsigned*)&ob[row * 136 + 2 * l] = pk2(acc0, acc1);
  }
  __syncthreads();
  // Wo MFMA epilogue: 16 waves, wave = (row-pair, col-tile)
  int lr = l & 15, lk = l >> 4;
  int ct = w & 7;                 // col tile 0..7
  int st0 = (w >> 3) * 2;         // row strips {st0, st0+1}
  int col = ct * 16 + lr;
  const short* ol = (const short*)ob;
  const short* wl = (const short*)wo;
  float4v acc[2] = {};
  short8v bfrag[4];
#pragma unroll
  for (int ks = 0; ks < 4; ++ks)
    bfrag[ks] = *(const short8v*)&wl[col * 136 + ks * 32 + lk * 8];
#pragma unroll
  for (int ks = 0; ks < 4; ++ks)
#pragma unroll
    for (int i = 0; i < 2; ++i) {
      short8v a = *(const short8v*)&ol[((st0 + i) * 16 + lr) * 136 + ks * 32 + lk * 8];
      acc[i] = __builtin_amdgcn_mfma_f32_16x16x32_bf16(a, bfrag[ks], acc[i], 0, 0, 0);
    }
  float* base = out + (size_t)OUT0 + (size_t)blockIdx.x * 64 * NE;
#pragma unroll
  for (int i = 0; i < 2; ++i)
#pragma unroll
    for (int r = 0; r < 4; ++r) {
      int row = (st0 + i) * 16 + lk * 4 + r;
      base[(size_t)row * NE + col] = acc[i][r];
    }
}

extern "C" void kernel_launch(void* const* d_in, const int* in_sizes, int n_in,
                              void* d_out, int out_size, void* d_ws, size_t ws_size,
                              hipStream_t stream) {
  const float* xc_off  = (const float*)d_in[0];
  const float* xc_on   = (const float*)d_in[1];
  const float* zc_off  = (const float*)d_in[2];
  const float* latents = (const float*)d_in[4];
  const float* fake    = (const float*)d_in[5];
  const float* Wq      = (const float*)d_in[6];
  const float* Wk      = (const float*)d_in[7];
  const float* Wv      = (const float*)d_in[8];
  const float* Wo      = (const float*)d_in[9];
  float* out = (float*)d_out;

  char* ws = (char*)d_ws;
  int*            counts = (int*)(ws);
  unsigned short* lists  = (unsigned short*)(ws + 131072);
  float*          S      = (float*)(ws + 1441792);
  __hip_bfloat16* G      = (__hip_bfloat16*)(ws + 3538944);
  float*          FS     = (float*)(ws + 11927552);
  float*          fakeKV = (float*)(ws + 12058624);
  __hip_bfloat16* Wvt    = (__hip_bfloat16*)(ws + 12059648);
  __hip_bfloat16* Wot    = (__hip_bfloat16*)(ws + 12092416);
  __hip_bfloat16* Vb     = (__hip_bfloat16*)(ws + 12125184);
  unsigned short* ps     = (unsigned short*)(ws + 28902400);

  hipLaunchKernelGGL(setup_kernel, dim3(OUT0 / 256), dim3(256), 0, stream,
                     xc_on, fake, Wk, Wv, Wo, out, counts, fakeKV, Wvt, Wot);
  hipLaunchKernelGGL(nearest_kernel, dim3(NPTS / 256), dim3(256), 0, stream,
                     xc_off, xc_on, counts, lists, ps);
  hipLaunchKernelGGL(prep_kernel, dim3(NS / 8), dim3(256), 0, stream,
                     latents, Wq, Wk, fakeKV, G, FS);
  hipLaunchKernelGGL(scores_kernel, dim3(NPTS / 4), dim3(256), 0, stream,
                     zc_off, ps, G, S);
  hipLaunchKernelGGL(vgemm_kernel, dim3(NPTS / 64), dim3(256), 0, stream,
                     zc_off, Wvt, Vb);
  hipLaunchKernelGGL(attn_wo_kernel, dim3(NCELL / 64), dim3(1024), 0, stream,
                     Vb, S, FS, fakeKV, counts, lists, Wot, out);
}